// Round 1
// baseline (756.522 us; speedup 1.0000x reference)
//
#include <hip/hip_runtime.h>
#include <stdint.h>

#define NCOLS 24576
#define TPB   512
#define VPT   (NCOLS / (TPB * 4))   // 12 uint4 per thread
#define EPT   (VPT * 4)             // 48 elements per thread
#define KSEL  64
#define CAP   1024

// monotonic float->uint key transform (total order, negatives below positives)
__device__ __forceinline__ uint32_t f2k(uint32_t b) {
  return (b & 0x80000000u) ? ~b : (b | 0x80000000u);
}
__device__ __forceinline__ float k2f(uint32_t k) {
  uint32_t b = (k & 0x80000000u) ? (k ^ 0x80000000u) : ~k;
  return __uint_as_float(b);
}

__global__ void __launch_bounds__(TPB, 4)
topk_relu_scatter(const float* __restrict__ x, float* __restrict__ out) {
  const int row = blockIdx.x;
  const int tid = threadIdx.x;
  const uint4* __restrict__ xr =
      reinterpret_cast<const uint4*>(x + (size_t)row * NCOLS);
  float4* __restrict__ orow =
      reinterpret_cast<float4*>(out + (size_t)row * NCOLS);

  // ---- load row: 12 coalesced uint4 per thread, transform to keys ----
  uint32_t key[EPT];
  #pragma unroll
  for (int i = 0; i < VPT; ++i) {
    uint4 v = xr[tid + TPB * i];
    key[4*i+0] = f2k(v.x);
    key[4*i+1] = f2k(v.y);
    key[4*i+2] = f2k(v.z);
    key[4*i+3] = f2k(v.w);
  }

  __shared__ int      s_part[TPB / 64];
  __shared__ int      s_cnt;
  __shared__ uint32_t s_candK[CAP];
  __shared__ int      s_candI[CAP];
  __shared__ int      s_m;
  __shared__ uint32_t s_k64;
  __shared__ int      s_c, s_e;
  __shared__ int      s_incIdx[KSEL];
  __shared__ int      s_ninc;
  __shared__ int      s_thrIdx;

  // block-wide count of keys >= thr (VALU compares + shuffle reduce)
  auto blockCount = [&](uint32_t thr) -> int {
    int c = 0;
    #pragma unroll
    for (int i = 0; i < EPT; ++i) c += (key[i] >= thr) ? 1 : 0;
    #pragma unroll
    for (int off = 32; off > 0; off >>= 1) c += __shfl_down(c, off, 64);
    if ((tid & 63) == 0) s_part[tid >> 6] = c;
    __syncthreads();
    if (tid == 0) {
      int t = 0;
      for (int w = 0; w < TPB / 64; ++w) t += s_part[w];
      s_cnt = t;
    }
    __syncthreads();
    return s_cnt;
  };

  // block-wide count of (key == eqv && col < idxLim)   [rare fallback path]
  auto blockCountEq = [&](uint32_t eqv, int idxLim) -> int {
    int c = 0;
    #pragma unroll
    for (int i = 0; i < EPT; ++i) {
      int col = 4 * (tid + TPB * (i >> 2)) + (i & 3);
      c += (key[i] == eqv && col < idxLim) ? 1 : 0;
    }
    #pragma unroll
    for (int off = 32; off > 0; off >>= 1) c += __shfl_down(c, off, 64);
    if ((tid & 63) == 0) s_part[tid >> 6] = c;
    __syncthreads();
    if (tid == 0) {
      int t = 0;
      for (int w = 0; w < TPB / 64; ++w) t += s_part[w];
      s_cnt = t;
    }
    __syncthreads();
    return s_cnt;
  };

  // ---- binary search for 64th-largest key, restricted to keys >= key(+0) ----
  // Invariant: if the true 64th key is >= 0x80000000 it lies in [lo,hi].
  // If it is negative, lo stays 0x80000000 and the uniform write rule below
  // degenerates to out = max(x,0), which is exactly correct after ReLU.
  uint32_t lo = 0x80000000u, hi = 0xFFFFFFFFu;
  int loCnt = NCOLS;  // count(keys >= lo), upper bound initially
  while (lo < hi) {
    uint32_t mid = lo + ((hi - lo) >> 1) + 1;  // in (lo, hi]
    int cnt = blockCount(mid);
    if (cnt >= KSEL) { lo = mid; loCnt = cnt; }
    else             { hi = mid - 1; }
    if (loCnt <= CAP) break;   // few enough survivors: gather & finish exactly
  }

  if (tid == 0) { s_m = 0; s_ninc = 0; }
  __syncthreads();

  uint32_t K64;
  int mode = 0;  // 0: include all equals; 1: LDS include-list; 2: col < s_thrIdx

  if (loCnt <= CAP) {
    // ---- gather candidates (all keys >= lo; superset of top-64) ----
    #pragma unroll
    for (int i = 0; i < EPT; ++i) {
      if (key[i] >= lo) {
        int p = atomicAdd(&s_m, 1);
        if (p < CAP) {
          s_candK[p] = key[i];
          s_candI[p] = 4 * (tid + TPB * (i >> 2)) + (i & 3);
        }
      }
    }
    __syncthreads();
    int m = s_m; if (m > CAP) m = CAP;
    // exact select: candidate whose strict-above rank r satisfies
    // r < 64 <= r + (#equal) is the 64th-largest value
    for (int p = tid; p < m; p += TPB) {
      uint32_t kk = s_candK[p];
      int r = 0, q = 0;
      for (int j = 0; j < m; ++j) {
        uint32_t kj = s_candK[j];
        r += (kj > kk) ? 1 : 0;
        q += (kj == kk) ? 1 : 0;
      }
      if (r < KSEL && r + q >= KSEL) { s_k64 = kk; s_c = r; s_e = q; }
    }
    __syncthreads();
    K64 = s_k64;
    int c = s_c, e = s_e;
    int needed = KSEL - c;
    if (e > needed) {
      // tie at threshold: include lowest-index `needed` equals (lax.top_k order)
      mode = 1;
      for (int p = tid; p < m; p += TPB) {
        if (s_candK[p] == K64) {
          int myi = s_candI[p];
          int rk = 0;
          for (int j = 0; j < m; ++j)
            if (s_candK[j] == K64 && s_candI[j] < myi) rk++;
          if (rk < needed) { int q2 = atomicAdd(&s_ninc, 1); s_incIdx[q2] = myi; }
        }
      }
      __syncthreads();
    }
  } else {
    // ---- window collapsed with many survivors (adversarial data only) ----
    K64 = lo;
    int c = (K64 == 0xFFFFFFFFu) ? 0 : blockCount(K64 + 1);
    #pragma unroll
    for (int i = 0; i < EPT; ++i) {
      if (key[i] == K64) {
        int p = atomicAdd(&s_m, 1);
        if (p < CAP) s_candI[p] = 4 * (tid + TPB * (i >> 2)) + (i & 3);
      }
    }
    __syncthreads();
    int e = s_m;
    int needed = KSEL - c;
    if (needed < 0) needed = 0;
    if (e > needed) {
      if (e <= CAP) {
        mode = 1;
        for (int p = tid; p < e; p += TPB) {
          int myi = s_candI[p];
          int rk = 0;
          for (int j = 0; j < e; ++j) if (s_candI[j] < myi) rk++;
          if (rk < needed) { int q2 = atomicAdd(&s_ninc, 1); s_incIdx[q2] = myi; }
        }
        __syncthreads();
      } else {
        // massive tie: binary search the column cutoff
        mode = 2;
        int ilo = 0, ihi = NCOLS;
        while (ilo < ihi) {
          int imid = (ilo + ihi) >> 1;
          int cq = blockCountEq(K64, imid);
          if (cq >= needed) ihi = imid; else ilo = imid + 1;
        }
        if (tid == 0) s_thrIdx = ilo;
        __syncthreads();
      }
    }
    // e == needed (or fewer positives than K exist): mode 0 include-all-equals
  }

  // ---- write output from registers: single coalesced float4 stream ----
  int ninc   = (mode == 1) ? s_ninc   : 0;
  int thrIdx = (mode == 2) ? s_thrIdx : 0;
  #pragma unroll
  for (int i = 0; i < VPT; ++i) {
    float v[4];
    #pragma unroll
    for (int j = 0; j < 4; ++j) {
      uint32_t kk = key[4*i+j];
      bool inc = kk > K64;
      if (kk == K64) {
        if (mode == 0) {
          inc = true;
        } else if (mode == 1) {
          int col = 4 * (tid + TPB * i) + j;
          for (int q2 = 0; q2 < ninc; ++q2)
            if (s_incIdx[q2] == col) { inc = true; break; }
        } else {
          inc = (4 * (tid + TPB * i) + j) < thrIdx;
        }
      }
      float f = k2f(kk);
      v[j] = inc ? fmaxf(f, 0.0f) : 0.0f;
    }
    float4 o = make_float4(v[0], v[1], v[2], v[3]);
    orow[tid + TPB * i] = o;
  }
}

extern "C" void kernel_launch(void* const* d_in, const int* in_sizes, int n_in,
                              void* d_out, int out_size, void* d_ws, size_t ws_size,
                              hipStream_t stream) {
  (void)in_sizes; (void)n_in; (void)d_ws; (void)ws_size;
  const float* x = (const float*)d_in[0];
  float* out = (float*)d_out;
  int nrows = out_size / NCOLS;  // 4096
  topk_relu_scatter<<<nrows, TPB, 0, stream>>>(x, out);
}

// Round 2
// 677.188 us; speedup vs baseline: 1.1172x; 1.1172x over previous
//
#include <hip/hip_runtime.h>
#include <stdint.h>

#define NCOLS 24576
#define TPB   512
#define VPT   (NCOLS / (TPB * 4))   // 12 uint4 per thread
#define EPT   (VPT * 4)             // 48 elements per thread
#define KSEL  64
#define CAP   1024
#define NWAVES (TPB / 64)

typedef uint32_t u32x4 __attribute__((ext_vector_type(4)));

// key transform: b ^ 0x80000000. Monotonic for non-negative floats (the only
// region we ever rank); negatives land below key(+0)=0x80000000 (order among
// them scrambled — irrelevant: they are never in the searched domain, and
// ReLU zeroes them). Involution: key ^ 0x80000000 restores original bits.

__global__ void __launch_bounds__(TPB, 4)
topk_relu_scatter(const float* __restrict__ x, float* __restrict__ out) {
  const int row  = blockIdx.x;
  const int tid  = threadIdx.x;
  const int lane = tid & 63;

  const uint4* __restrict__ xr =
      reinterpret_cast<const uint4*>(x + (size_t)row * NCOLS);
  u32x4* __restrict__ orow =
      reinterpret_cast<u32x4*>(out + (size_t)row * NCOLS);

  // ---- load row: 12 coalesced uint4 per thread, transform to keys ----
  uint32_t key[EPT];
  #pragma unroll
  for (int i = 0; i < VPT; ++i) {
    uint4 v = xr[tid + TPB * i];
    key[4*i+0] = v.x ^ 0x80000000u;
    key[4*i+1] = v.y ^ 0x80000000u;
    key[4*i+2] = v.z ^ 0x80000000u;
    key[4*i+3] = v.w ^ 0x80000000u;
  }

  __shared__ int      s_part[NWAVES];
  __shared__ int      s_cnt;
  __shared__ uint32_t s_candK[CAP];
  __shared__ int      s_candI[CAP];
  __shared__ int      s_m;
  __shared__ uint32_t s_k64;
  __shared__ int      s_c, s_e;
  __shared__ int      s_incIdx[KSEL];
  __shared__ int      s_ninc;
  __shared__ int      s_thrIdx;

  // block-wide count of keys >= thr
  auto blockCount = [&](uint32_t thr) -> int {
    int c = 0;
    #pragma unroll
    for (int i = 0; i < EPT; ++i) c += (key[i] >= thr) ? 1 : 0;
    #pragma unroll
    for (int off = 32; off > 0; off >>= 1) c += __shfl_down(c, off, 64);
    if ((tid & 63) == 0) s_part[tid >> 6] = c;
    __syncthreads();
    if (tid == 0) {
      int t = 0;
      for (int w = 0; w < NWAVES; ++w) t += s_part[w];
      s_cnt = t;
    }
    __syncthreads();
    return s_cnt;
  };

  // block-wide count of (key == eqv && col < idxLim)  [rare fallback only]
  auto blockCountEq = [&](uint32_t eqv, int idxLim) -> int {
    int c = 0;
    #pragma unroll
    for (int i = 0; i < EPT; ++i) {
      int col = 4 * (tid + TPB * (i >> 2)) + (i & 3);
      c += (key[i] == eqv && col < idxLim) ? 1 : 0;
    }
    #pragma unroll
    for (int off = 32; off > 0; off >>= 1) c += __shfl_down(c, off, 64);
    if ((tid & 63) == 0) s_part[tid >> 6] = c;
    __syncthreads();
    if (tid == 0) {
      int t = 0;
      for (int w = 0; w < NWAVES; ++w) t += s_part[w];
      s_cnt = t;
    }
    __syncthreads();
    return s_cnt;
  };

  if (tid == 0) { s_m = 0; s_ninc = 0; }
  // ordering note: the search loop below always executes >=1 blockCount,
  // whose two __syncthreads order this init before any atomicAdd(&s_m).

  // ---- coarse binary search until survivors fit in CAP ----
  // Invariant: count(>= lo) >= KSEL whenever loCnt was updated; domain is
  // keys >= key(+0). If <64 non-negatives exist the window collapses to
  // lo = 0x80000000 and the fallback degenerates to out = max(x,0): exact.
  uint32_t lo = 0x80000000u, hi = 0xFFFFFFFFu;
  int loCnt = NCOLS;  // sentinel upper bound
  while (lo < hi) {
    uint32_t mid = lo + ((hi - lo) >> 1) + 1;  // in (lo, hi]
    int cnt = blockCount(mid);
    if (cnt >= KSEL) { lo = mid; loCnt = cnt; }
    else             { hi = mid - 1; }
    if (loCnt <= CAP) break;   // Gaussian data: first pivot (2.0f) -> ~560
  }

  uint32_t K64;
  int mode = 0;  // 0: include all >= K64; 1: LDS include-list; 2: col < thrIdx

  if (loCnt <= CAP) {
    // ---- gather survivors; m == loCnt <= CAP exactly ----
    #pragma unroll
    for (int i = 0; i < EPT; ++i) {
      if (key[i] >= lo) {
        int p = atomicAdd(&s_m, 1);
        if (p < CAP) {
          s_candK[p] = key[i];
          s_candI[p] = 4 * (tid + TPB * (i >> 2)) + (i & 3);
        }
      }
    }
    __syncthreads();
    int m = s_m; if (m > CAP) m = CAP;

    // ---- single-wave SGPR-ballot binary search for the 64th key ----
    if (tid < 64) {
      uint32_t cnd[16];
      #pragma unroll
      for (int j = 0; j < 16; ++j) {
        int idx = lane + 64 * j;              // strided: 2-way bank alias, free
        uint32_t v = s_candK[idx];            // uninit beyond m: masked below
        cnd[j] = (idx < m) ? v : 0u;          // pad 0 < any searched mid
      }
      uint32_t slo = lo, shi = 0xFFFFFFFFu;
      while (slo < shi) {
        uint32_t mid = slo + ((shi - slo) >> 1) + 1;
        int cnt = 0;
        #pragma unroll
        for (int j = 0; j < 16; ++j)
          cnt += (int)__popcll(__ballot(cnd[j] >= mid));
        if (cnt >= KSEL) slo = mid; else shi = mid - 1;
      }
      int cge = 0, cgt = 0;
      #pragma unroll
      for (int j = 0; j < 16; ++j) {
        cge += (int)__popcll(__ballot(cnd[j] >= slo));
        cgt += (int)__popcll(__ballot(cnd[j] >  slo));
      }
      if (lane == 0) { s_k64 = slo; s_c = cgt; s_e = cge - cgt; }
    }
    __syncthreads();
    K64 = s_k64;
    int c = s_c, e = s_e;
    int needed = KSEL - c;
    if (e > needed) {
      // tie at threshold: include lowest-index `needed` equals (lax.top_k order)
      mode = 1;
      for (int p = tid; p < m; p += TPB) {
        if (s_candK[p] == K64) {
          int myi = s_candI[p];
          int rk = 0;
          for (int j = 0; j < m; ++j)
            if (s_candK[j] == K64 && s_candI[j] < myi) rk++;
          if (rk < needed) { int q2 = atomicAdd(&s_ninc, 1); s_incIdx[q2] = myi; }
        }
      }
      __syncthreads();
    }
  } else {
    // ---- window collapsed with many survivors (adversarial data only) ----
    K64 = lo;
    int c = (K64 == 0xFFFFFFFFu) ? 0 : blockCount(K64 + 1);
    #pragma unroll
    for (int i = 0; i < EPT; ++i) {
      if (key[i] == K64) {
        int p = atomicAdd(&s_m, 1);
        if (p < CAP) s_candI[p] = 4 * (tid + TPB * (i >> 2)) + (i & 3);
      }
    }
    __syncthreads();
    int e = s_m;
    int needed = KSEL - c;
    if (needed < 0) needed = 0;
    if (e > needed) {
      if (e <= CAP) {
        mode = 1;
        for (int p = tid; p < e; p += TPB) {
          int myi = s_candI[p];
          int rk = 0;
          for (int j = 0; j < e; ++j) if (s_candI[j] < myi) rk++;
          if (rk < needed) { int q2 = atomicAdd(&s_ninc, 1); s_incIdx[q2] = myi; }
        }
        __syncthreads();
      } else {
        // massive tie: binary search the column cutoff
        mode = 2;
        int ilo = 0, ihi = NCOLS;
        while (ilo < ihi) {
          int imid = (ilo + ihi) >> 1;
          int cq = blockCountEq(K64, imid);
          if (cq >= needed) ihi = imid; else ilo = imid + 1;
        }
        if (tid == 0) s_thrIdx = ilo;
        __syncthreads();
      }
    }
    // e == needed (or fewer than K positives): mode 0 include-all-equals
  }

  // ---- write output from registers: coalesced NT uint4 stream ----
  // Included implies kk >= K64 >= 0x80000000 => original float >= +0.0, so
  // relu(f) == f and the stored bits are exactly kk ^ 0x80000000.
  if (mode == 0) {
    #pragma unroll
    for (int i = 0; i < VPT; ++i) {
      u32x4 o;
      #pragma unroll
      for (int j = 0; j < 4; ++j) {
        uint32_t kk = key[4*i+j];
        o[j] = (kk >= K64) ? (kk ^ 0x80000000u) : 0u;
      }
      __builtin_nontemporal_store(o, &orow[tid + TPB * i]);
    }
  } else {
    int ninc   = (mode == 1) ? s_ninc   : 0;
    int thrIdx = (mode == 2) ? s_thrIdx : 0;
    #pragma unroll
    for (int i = 0; i < VPT; ++i) {
      u32x4 o;
      #pragma unroll
      for (int j = 0; j < 4; ++j) {
        uint32_t kk = key[4*i+j];
        bool inc = kk > K64;
        if (kk == K64) {
          int col = 4 * (tid + TPB * i) + j;
          if (mode == 1) {
            for (int q2 = 0; q2 < ninc; ++q2)
              if (s_incIdx[q2] == col) { inc = true; break; }
          } else {
            inc = col < thrIdx;
          }
        }
        o[j] = inc ? (kk ^ 0x80000000u) : 0u;
      }
      __builtin_nontemporal_store(o, &orow[tid + TPB * i]);
    }
  }
}

extern "C" void kernel_launch(void* const* d_in, const int* in_sizes, int n_in,
                              void* d_out, int out_size, void* d_ws, size_t ws_size,
                              hipStream_t stream) {
  (void)in_sizes; (void)n_in; (void)d_ws; (void)ws_size;
  const float* x = (const float*)d_in[0];
  float* out = (float*)d_out;
  int nrows = out_size / NCOLS;  // 4096
  topk_relu_scatter<<<nrows, TPB, 0, stream>>>(x, out);
}